// Round 2
// baseline (259.661 us; speedup 1.0000x reference)
//
#include <hip/hip_runtime.h>
#include <math.h>

#define C 4096

typedef float f4 __attribute__((ext_vector_type(4)));

// Force all 16 row-fragments to be simultaneously live in VGPRs. This is a
// register-allocation constraint, not a scheduler hint: the compiler MUST
// issue all 16 dwordx4 loads before this point and keep 64 VGPRs of data
// live (one s_waitcnt vmcnt(0), then pure-register consume). Round-1's
// sched_barrier(0) failed to achieve this (VGPR stayed 40 => <=6 loads in
// flight); this construct cannot be circumvented without visible spills.
#define FORCE_LIVE16(w)                                                      \
    asm volatile("" ::                                                       \
        "v"(w[0]), "v"(w[1]), "v"(w[2]), "v"(w[3]),                          \
        "v"(w[4]), "v"(w[5]), "v"(w[6]), "v"(w[7]),                          \
        "v"(w[8]), "v"(w[9]), "v"(w[10]), "v"(w[11]),                        \
        "v"(w[12]), "v"(w[13]), "v"(w[14]), "v"(w[15]))

// ---------------------------------------------------------------------------
// Kernel 1: fused token-shift mix + three matvecs (kw@xk, vw@xv, rw@xr).
// Grid: 3072 blocks of 256. Block b: matrix m = b>>10, rows (b&1023)*4 .. +3,
// one wave per row, whole 16 KiB row staged in registers (16 dwordx4 deep).
// ---------------------------------------------------------------------------
__global__ __launch_bounds__(256) void matvec3_kernel(
    const float* __restrict__ kw, const float* __restrict__ vw, const float* __restrict__ rw,
    const float* __restrict__ x, const float* __restrict__ state,
    const float* __restrict__ tmk, const float* __restrict__ tmv, const float* __restrict__ tmr,
    float* __restrict__ kk, float* __restrict__ vvo, float* __restrict__ rr) {
    __shared__ f4 xs[C / 4];   // 16 KiB: mixed input vector

    const int t = threadIdx.x;
    const int m = blockIdx.x >> 10;

    const float* W;
    const float* tm;
    float* out;
    if (m == 0)      { W = kw; tm = tmk; out = kk;  }
    else if (m == 1) { W = vw; tm = tmv; out = vvo; }
    else             { W = rw; tm = tmr; out = rr;  }

    // Stage mixed vector: xm = x*tm + state*(1-tm)
    const f4* x4 = (const f4*)x;
    const f4* s4 = (const f4*)state;
    const f4* t4 = (const f4*)tm;
#pragma unroll
    for (int j = 0; j < 4; ++j) {
        int i = j * 256 + t;
        f4 xi = x4[i], si = s4[i], ti = t4[i];
        f4 r;
        r.x = xi.x * ti.x + si.x * (1.0f - ti.x);
        r.y = xi.y * ti.y + si.y * (1.0f - ti.y);
        r.z = xi.z * ti.z + si.z * (1.0f - ti.z);
        r.w = xi.w * ti.w + si.w * (1.0f - ti.w);
        xs[i] = r;
    }
    __syncthreads();

    const int wave = t >> 6;
    const int lane = t & 63;
    const int row  = (blockIdx.x & 1023) * 4 + wave;
    const f4* Wrow = (const f4*)(W + (size_t)row * C);

    // Issue the entire row's loads (16 independent dwordx4, 16 KiB in flight).
    f4 wreg[16];
#pragma unroll
    for (int it = 0; it < 16; ++it) wreg[it] = Wrow[it * 64 + lane];
    FORCE_LIVE16(wreg);

    // Consume against LDS copies of x, 4 independent accumulator chains.
    float s0 = 0.f, s1 = 0.f, s2 = 0.f, s3 = 0.f;
#pragma unroll
    for (int it = 0; it < 16; ++it) {
        f4 xx = xs[it * 64 + lane];
        f4 w  = wreg[it];
        s0 += w.x * xx.x;
        s1 += w.y * xx.y;
        s2 += w.z * xx.z;
        s3 += w.w * xx.w;
    }
    float sum = (s0 + s1) + (s2 + s3);
#pragma unroll
    for (int off = 32; off > 0; off >>= 1) sum += __shfl_down(sum, off, 64);
    if (lane == 0) out[row] = sum;
}

// ---------------------------------------------------------------------------
// Kernel 2: WKV elementwise core + state updates + new_state = x
// ---------------------------------------------------------------------------
__global__ void wkv_kernel(const float* __restrict__ kk, const float* __restrict__ vv,
                           const float* __restrict__ rr,
                           const float* __restrict__ aa, const float* __restrict__ bb,
                           const float* __restrict__ pp,
                           const float* __restrict__ time_first,
                           const float* __restrict__ time_decay,
                           const float* __restrict__ x,
                           float* __restrict__ rwkv,
                           float* __restrict__ new_state,
                           float* __restrict__ out_sa, float* __restrict__ out_sb,
                           float* __restrict__ out_sp) {
    int i = blockIdx.x * blockDim.x + threadIdx.x;
    if (i < C) {
        float k = kk[i], v = vv[i];
        float a_ = aa[i], b_ = bb[i], p_ = pp[i];

        float ww = time_first[i] + k;
        float p  = fmaxf(p_, ww);
        float e1 = expf(p_ - p);
        float e2 = expf(ww - p);
        float a  = e1 * a_ + e2 * v;
        float b  = e1 * b_ + e2;

        float ww2 = p_ + time_decay[i];
        float p2  = fmaxf(ww2, k);
        float e1b = expf(ww2 - p2);
        float e2b = expf(k - p2);
        out_sa[i] = e1b * a_ + e2b * v;
        out_sb[i] = e1b * b_ + e2b;
        out_sp[i] = p2;

        new_state[i] = x[i];

        float r = 1.0f / (1.0f + expf(-rr[i]));
        rwkv[i] = r * (a / b);
    }
}

// ---------------------------------------------------------------------------
// Kernel 3: final matvec ow @ (r*wkv) -> out. Same GEMV core, rwkv via LDS.
// ow loads stay nontemporal (zero reuse; keep kw/vw/rw L3-resident).
// ---------------------------------------------------------------------------
__global__ __launch_bounds__(256) void matvec_kernel(const float* __restrict__ W,
                                                     const float* __restrict__ xin,
                                                     float* __restrict__ out) {
    __shared__ f4 xs[C / 4];
    const int t = threadIdx.x;

    const f4* x4 = (const f4*)xin;
#pragma unroll
    for (int j = 0; j < 4; ++j) {
        int i = j * 256 + t;
        xs[i] = x4[i];
    }
    __syncthreads();

    const int wave = t >> 6;
    const int lane = t & 63;
    const int row  = blockIdx.x * 4 + wave;
    const f4* Wrow = (const f4*)(W + (size_t)row * C);

    f4 wreg[16];
#pragma unroll
    for (int it = 0; it < 16; ++it)
        wreg[it] = __builtin_nontemporal_load(&Wrow[it * 64 + lane]);
    FORCE_LIVE16(wreg);

    float s0 = 0.f, s1 = 0.f, s2 = 0.f, s3 = 0.f;
#pragma unroll
    for (int it = 0; it < 16; ++it) {
        f4 xx = xs[it * 64 + lane];
        f4 w  = wreg[it];
        s0 += w.x * xx.x;
        s1 += w.y * xx.y;
        s2 += w.z * xx.z;
        s3 += w.w * xx.w;
    }
    float sum = (s0 + s1) + (s2 + s3);
#pragma unroll
    for (int off = 32; off > 0; off >>= 1) sum += __shfl_down(sum, off, 64);
    if (lane == 0) out[row] = sum;
}

// ---------------------------------------------------------------------------
extern "C" void kernel_launch(void* const* d_in, const int* in_sizes, int n_in,
                              void* d_out, int out_size, void* d_ws, size_t ws_size,
                              hipStream_t stream) {
    const float* x          = (const float*)d_in[0];
    const float* state      = (const float*)d_in[1];
    const float* state_a    = (const float*)d_in[2];
    const float* state_b    = (const float*)d_in[3];
    const float* state_p    = (const float*)d_in[4];
    const float* tmk        = (const float*)d_in[5];
    const float* tmv        = (const float*)d_in[6];
    const float* tmr        = (const float*)d_in[7];
    const float* time_first = (const float*)d_in[8];
    const float* time_decay = (const float*)d_in[9];
    const float* kw         = (const float*)d_in[10];
    const float* vw         = (const float*)d_in[11];
    const float* rw         = (const float*)d_in[12];
    const float* ow         = (const float*)d_in[13];

    float* out       = (float*)d_out;        // [0:C)     out
    float* new_state = out + C;              // [C:2C)    new_state = x
    float* new_sa    = out + 2 * C;          // [2C:3C)   new_state_a
    float* new_sb    = out + 3 * C;          // [3C:4C)   new_state_b
    float* new_sp    = out + 4 * C;          // [4C:5C)   new_state_p

    float* ws   = (float*)d_ws;
    float* kk   = ws;
    float* vv   = ws + C;
    float* rr   = ws + 2 * C;
    float* rwkv = ws + 3 * C;

    matvec3_kernel<<<3 * C / 4, 256, 0, stream>>>(kw, vw, rw, x, state, tmk, tmv, tmr,
                                                  kk, vv, rr);

    wkv_kernel<<<C / 256, 256, 0, stream>>>(kk, vv, rr, state_a, state_b, state_p,
                                            time_first, time_decay, x,
                                            rwkv, new_state, new_sa, new_sb, new_sp);

    matvec_kernel<<<C / 4, 256, 0, stream>>>(ow, rwkv, out);
}

// Round 3
// 259.436 us; speedup vs baseline: 1.0009x; 1.0009x over previous
//
#include <hip/hip_runtime.h>
#include <math.h>

#define C 4096

typedef float f4 __attribute__((ext_vector_type(4)));

// ---------------------------------------------------------------------------
// Kernel 1: fused token-shift mix + three matvecs (kw@xk, vw@xv, rw@xr).
//
// STREAM form (round 3): the two previous rounds proved that forcing deeper
// load bursts does nothing (VGPR/dur immovable). This version abandons the
// burst+wait-all structure entirely and mimics the m13 copy-kernel shape:
//   - each wave streams TWO rows with loads+FMAs interleaved -> there is
//     always an independent load ready to issue (continuous demand),
//   - no vmcnt(0) convoy, no FORCE_LIVE fence,
//   - grid = 6 blocks/CU exactly (1536 blocks), __launch_bounds__(256,6)
//     => 24 waves/CU resident (75% occupancy) in a single clean round,
//   - one 48 KB x-staging amortized over 8 rows (128 KB of weights) instead
//     of 4.
// ---------------------------------------------------------------------------
__global__ __launch_bounds__(256, 6) void matvec3_kernel(
    const float* __restrict__ kw, const float* __restrict__ vw, const float* __restrict__ rw,
    const float* __restrict__ x, const float* __restrict__ state,
    const float* __restrict__ tmk, const float* __restrict__ tmv, const float* __restrict__ tmr,
    float* __restrict__ kk, float* __restrict__ vvo, float* __restrict__ rr) {
    __shared__ f4 xs[C / 4];   // 16 KiB: mixed input vector

    const int t = threadIdx.x;
    // 1536 blocks: 512 per matrix. m = blockIdx.x >> 9, row-group = bid & 511.
    const int m = blockIdx.x >> 9;

    const float* W;
    const float* tm;
    float* out;
    if (m == 0)      { W = kw; tm = tmk; out = kk;  }
    else if (m == 1) { W = vw; tm = tmv; out = vvo; }
    else             { W = rw; tm = tmr; out = rr;  }

    // Stage mixed vector: xm = x*tm + state*(1-tm)
    const f4* x4 = (const f4*)x;
    const f4* s4 = (const f4*)state;
    const f4* t4 = (const f4*)tm;
#pragma unroll
    for (int j = 0; j < 4; ++j) {
        int i = j * 256 + t;
        f4 xi = x4[i], si = s4[i], ti = t4[i];
        f4 r;
        r.x = xi.x * ti.x + si.x * (1.0f - ti.x);
        r.y = xi.y * ti.y + si.y * (1.0f - ti.y);
        r.z = xi.z * ti.z + si.z * (1.0f - ti.z);
        r.w = xi.w * ti.w + si.w * (1.0f - ti.w);
        xs[i] = r;
    }
    __syncthreads();

    const int wave = t >> 6;
    const int lane = t & 63;
    // 8 rows per block, 2 interleaved rows per wave.
    const int r0 = (blockIdx.x & 511) * 8 + wave * 2;
    const int r1 = r0 + 1;
    const f4* W0 = (const f4*)(W + (size_t)r0 * C);
    const f4* W1 = (const f4*)(W + (size_t)r1 * C);

    f4 acc0 = {0.f, 0.f, 0.f, 0.f};
    f4 acc1 = {0.f, 0.f, 0.f, 0.f};
#pragma unroll
    for (int it = 0; it < 16; ++it) {
        f4 w0 = W0[it * 64 + lane];
        f4 w1 = W1[it * 64 + lane];
        f4 xx = xs[it * 64 + lane];
        acc0.x += w0.x * xx.x; acc0.y += w0.y * xx.y;
        acc0.z += w0.z * xx.z; acc0.w += w0.w * xx.w;
        acc1.x += w1.x * xx.x; acc1.y += w1.y * xx.y;
        acc1.z += w1.z * xx.z; acc1.w += w1.w * xx.w;
    }
    float sum0 = (acc0.x + acc0.y) + (acc0.z + acc0.w);
    float sum1 = (acc1.x + acc1.y) + (acc1.z + acc1.w);
#pragma unroll
    for (int off = 32; off > 0; off >>= 1) {
        sum0 += __shfl_down(sum0, off, 64);
        sum1 += __shfl_down(sum1, off, 64);
    }
    if (lane == 0) { out[r0] = sum0; out[r1] = sum1; }
}

// ---------------------------------------------------------------------------
// Kernel 2: WKV elementwise core + state updates + new_state = x
// ---------------------------------------------------------------------------
__global__ void wkv_kernel(const float* __restrict__ kk, const float* __restrict__ vv,
                           const float* __restrict__ rr,
                           const float* __restrict__ aa, const float* __restrict__ bb,
                           const float* __restrict__ pp,
                           const float* __restrict__ time_first,
                           const float* __restrict__ time_decay,
                           const float* __restrict__ x,
                           float* __restrict__ rwkv,
                           float* __restrict__ new_state,
                           float* __restrict__ out_sa, float* __restrict__ out_sb,
                           float* __restrict__ out_sp) {
    int i = blockIdx.x * blockDim.x + threadIdx.x;
    if (i < C) {
        float k = kk[i], v = vv[i];
        float a_ = aa[i], b_ = bb[i], p_ = pp[i];

        float ww = time_first[i] + k;
        float p  = fmaxf(p_, ww);
        float e1 = expf(p_ - p);
        float e2 = expf(ww - p);
        float a  = e1 * a_ + e2 * v;
        float b  = e1 * b_ + e2;

        float ww2 = p_ + time_decay[i];
        float p2  = fmaxf(ww2, k);
        float e1b = expf(ww2 - p2);
        float e2b = expf(k - p2);
        out_sa[i] = e1b * a_ + e2b * v;
        out_sb[i] = e1b * b_ + e2b;
        out_sp[i] = p2;

        new_state[i] = x[i];

        float r = 1.0f / (1.0f + expf(-rr[i]));
        rwkv[i] = r * (a / b);
    }
}

// ---------------------------------------------------------------------------
// Kernel 3: final matvec ow @ (r*wkv) -> out. Same stream form: 2 interleaved
// rows per wave, 8 rows per block, grid 512 (2 blocks/CU).
// ---------------------------------------------------------------------------
__global__ __launch_bounds__(256, 6) void matvec_kernel(const float* __restrict__ W,
                                                        const float* __restrict__ xin,
                                                        float* __restrict__ out) {
    __shared__ f4 xs[C / 4];
    const int t = threadIdx.x;

    const f4* x4 = (const f4*)xin;
#pragma unroll
    for (int j = 0; j < 4; ++j) {
        int i = j * 256 + t;
        xs[i] = x4[i];
    }
    __syncthreads();

    const int wave = t >> 6;
    const int lane = t & 63;
    const int r0 = blockIdx.x * 8 + wave * 2;
    const int r1 = r0 + 1;
    const f4* W0 = (const f4*)(W + (size_t)r0 * C);
    const f4* W1 = (const f4*)(W + (size_t)r1 * C);

    f4 acc0 = {0.f, 0.f, 0.f, 0.f};
    f4 acc1 = {0.f, 0.f, 0.f, 0.f};
#pragma unroll
    for (int it = 0; it < 16; ++it) {
        f4 w0 = W0[it * 64 + lane];
        f4 w1 = W1[it * 64 + lane];
        f4 xx = xs[it * 64 + lane];
        acc0.x += w0.x * xx.x; acc0.y += w0.y * xx.y;
        acc0.z += w0.z * xx.z; acc0.w += w0.w * xx.w;
        acc1.x += w1.x * xx.x; acc1.y += w1.y * xx.y;
        acc1.z += w1.z * xx.z; acc1.w += w1.w * xx.w;
    }
    float sum0 = (acc0.x + acc0.y) + (acc0.z + acc0.w);
    float sum1 = (acc1.x + acc1.y) + (acc1.z + acc1.w);
#pragma unroll
    for (int off = 32; off > 0; off >>= 1) {
        sum0 += __shfl_down(sum0, off, 64);
        sum1 += __shfl_down(sum1, off, 64);
    }
    if (lane == 0) { out[r0] = sum0; out[r1] = sum1; }
}

// ---------------------------------------------------------------------------
extern "C" void kernel_launch(void* const* d_in, const int* in_sizes, int n_in,
                              void* d_out, int out_size, void* d_ws, size_t ws_size,
                              hipStream_t stream) {
    const float* x          = (const float*)d_in[0];
    const float* state      = (const float*)d_in[1];
    const float* state_a    = (const float*)d_in[2];
    const float* state_b    = (const float*)d_in[3];
    const float* state_p    = (const float*)d_in[4];
    const float* tmk        = (const float*)d_in[5];
    const float* tmv        = (const float*)d_in[6];
    const float* tmr        = (const float*)d_in[7];
    const float* time_first = (const float*)d_in[8];
    const float* time_decay = (const float*)d_in[9];
    const float* kw         = (const float*)d_in[10];
    const float* vw         = (const float*)d_in[11];
    const float* rw         = (const float*)d_in[12];
    const float* ow         = (const float*)d_in[13];

    float* out       = (float*)d_out;        // [0:C)     out
    float* new_state = out + C;              // [C:2C)    new_state = x
    float* new_sa    = out + 2 * C;          // [2C:3C)   new_state_a
    float* new_sb    = out + 3 * C;          // [3C:4C)   new_state_b
    float* new_sp    = out + 4 * C;          // [4C:5C)   new_state_p

    float* ws   = (float*)d_ws;
    float* kk   = ws;
    float* vv   = ws + C;
    float* rr   = ws + 2 * C;
    float* rwkv = ws + 3 * C;

    // 1536 blocks = 6/CU exactly; 512 blocks per matrix, 8 rows per block.
    matvec3_kernel<<<3 * C / 8, 256, 0, stream>>>(kw, vw, rw, x, state, tmk, tmv, tmr,
                                                  kk, vv, rr);

    wkv_kernel<<<C / 256, 256, 0, stream>>>(kk, vv, rr, state_a, state_b, state_p,
                                            time_first, time_decay, x,
                                            rwkv, new_state, new_sa, new_sb, new_sp);

    matvec_kernel<<<C / 8, 256, 0, stream>>>(ow, rwkv, out);
}

// Round 4
// 259.122 us; speedup vs baseline: 1.0021x; 1.0012x over previous
//
#include <hip/hip_runtime.h>
#include <math.h>

#define C 4096

typedef float f4 __attribute__((ext_vector_type(4)));

// ---------------------------------------------------------------------------
// Kernel 1: fused token-shift mix + three matvecs (kw@xk, vw@xv, rw@xr).
// Best-measured form (round 3): 1536 blocks (6/CU), 8 rows/block, each wave
// streams 2 interleaved rows (continuous load demand, no wait-all convoy).
// Measured 67-69 us = 2.96 TB/s aggregate read ~ 94% of the read-direction
// fabric ceiling (m13's 6.29 TB/s copy = 3.15 read + 3.15 write). Frozen.
// ---------------------------------------------------------------------------
__global__ __launch_bounds__(256, 6) void matvec3_kernel(
    const float* __restrict__ kw, const float* __restrict__ vw, const float* __restrict__ rw,
    const float* __restrict__ x, const float* __restrict__ state,
    const float* __restrict__ tmk, const float* __restrict__ tmv, const float* __restrict__ tmr,
    float* __restrict__ kk, float* __restrict__ vvo, float* __restrict__ rr) {
    __shared__ f4 xs[C / 4];   // 16 KiB: mixed input vector

    const int t = threadIdx.x;
    const int m = blockIdx.x >> 9;   // 512 blocks per matrix

    const float* W;
    const float* tm;
    float* out;
    if (m == 0)      { W = kw; tm = tmk; out = kk;  }
    else if (m == 1) { W = vw; tm = tmv; out = vvo; }
    else             { W = rw; tm = tmr; out = rr;  }

    // Stage mixed vector: xm = x*tm + state*(1-tm)
    const f4* x4 = (const f4*)x;
    const f4* s4 = (const f4*)state;
    const f4* t4 = (const f4*)tm;
#pragma unroll
    for (int j = 0; j < 4; ++j) {
        int i = j * 256 + t;
        f4 xi = x4[i], si = s4[i], ti = t4[i];
        f4 r;
        r.x = xi.x * ti.x + si.x * (1.0f - ti.x);
        r.y = xi.y * ti.y + si.y * (1.0f - ti.y);
        r.z = xi.z * ti.z + si.z * (1.0f - ti.z);
        r.w = xi.w * ti.w + si.w * (1.0f - ti.w);
        xs[i] = r;
    }
    __syncthreads();

    const int wave = t >> 6;
    const int lane = t & 63;
    const int r0 = (blockIdx.x & 511) * 8 + wave * 2;
    const int r1 = r0 + 1;
    const f4* W0 = (const f4*)(W + (size_t)r0 * C);
    const f4* W1 = (const f4*)(W + (size_t)r1 * C);

    f4 acc0 = {0.f, 0.f, 0.f, 0.f};
    f4 acc1 = {0.f, 0.f, 0.f, 0.f};
#pragma unroll
    for (int it = 0; it < 16; ++it) {
        f4 w0 = W0[it * 64 + lane];
        f4 w1 = W1[it * 64 + lane];
        f4 xx = xs[it * 64 + lane];
        acc0.x += w0.x * xx.x; acc0.y += w0.y * xx.y;
        acc0.z += w0.z * xx.z; acc0.w += w0.w * xx.w;
        acc1.x += w1.x * xx.x; acc1.y += w1.y * xx.y;
        acc1.z += w1.z * xx.z; acc1.w += w1.w * xx.w;
    }
    float sum0 = (acc0.x + acc0.y) + (acc0.z + acc0.w);
    float sum1 = (acc1.x + acc1.y) + (acc1.z + acc1.w);
#pragma unroll
    for (int off = 32; off > 0; off >>= 1) {
        sum0 += __shfl_down(sum0, off, 64);
        sum1 += __shfl_down(sum1, off, 64);
    }
    if (lane == 0) { out[r0] = sum0; out[r1] = sum1; }
}

// ---------------------------------------------------------------------------
// Kernel 2 (fused): WKV elementwise core computed per-block straight into the
// LDS x-stage, then ow @ (r*wkv). Removes the standalone wkv kernel, its
// launch bubble, and the rwkv global round-trip. The wkv math is redundant
// across blocks (deterministic, identical results); the 8 input vectors are
// 128 KB broadcast through L2 (~1 MB/XCD of fabric traffic). Block 0 also
// writes the four state outputs.
// Grid: 1024 blocks (4/CU), 4 rows/block, 1 row per wave, burst-16 core.
// ---------------------------------------------------------------------------
__global__ __launch_bounds__(256) void wkv_matvec_kernel(
    const float* __restrict__ W,
    const float* __restrict__ kk, const float* __restrict__ vv, const float* __restrict__ rr,
    const float* __restrict__ aa, const float* __restrict__ bb, const float* __restrict__ pp,
    const float* __restrict__ time_first, const float* __restrict__ time_decay,
    const float* __restrict__ x,
    float* __restrict__ out, float* __restrict__ new_state,
    float* __restrict__ out_sa, float* __restrict__ out_sb, float* __restrict__ out_sp) {
    __shared__ f4 xs[C / 4];   // 16 KiB: r * wkv
    const int t = threadIdx.x;
    const bool writer = (blockIdx.x == 0);

    const f4* kk4 = (const f4*)kk;
    const f4* vv4 = (const f4*)vv;
    const f4* rr4 = (const f4*)rr;
    const f4* aa4 = (const f4*)aa;
    const f4* bb4 = (const f4*)bb;
    const f4* pp4 = (const f4*)pp;
    const f4* tf4 = (const f4*)time_first;
    const f4* td4 = (const f4*)time_decay;
    const f4* x4  = (const f4*)x;
    f4* sa4 = (f4*)out_sa;
    f4* sb4 = (f4*)out_sb;
    f4* sp4 = (f4*)out_sp;
    f4* ns4 = (f4*)new_state;

#pragma unroll
    for (int j = 0; j < 4; ++j) {
        int i = j * 256 + t;
        f4 kf = kk4[i], vf = vv4[i], rf = rr4[i];
        f4 af = aa4[i], bf = bb4[i], pf = pp4[i];
        f4 tff = tf4[i], tdf = td4[i];
        f4 rwkv, sa, sb, sp;

#define WKV1(cc)                                                             \
        {                                                                    \
            float k = kf.cc, v = vf.cc;                                      \
            float A = af.cc, B = bf.cc, P = pf.cc;                           \
            float ww = tff.cc + k;                                           \
            float p  = fmaxf(P, ww);                                         \
            float e1 = expf(P - p);                                          \
            float e2 = expf(ww - p);                                         \
            float a  = e1 * A + e2 * v;                                      \
            float b  = e1 * B + e2;                                          \
            float ww2 = P + tdf.cc;                                          \
            float p2  = fmaxf(ww2, k);                                       \
            float e1b = expf(ww2 - p2);                                      \
            float e2b = expf(k - p2);                                        \
            sa.cc = e1b * A + e2b * v;                                       \
            sb.cc = e1b * B + e2b;                                           \
            sp.cc = p2;                                                      \
            float r = 1.0f / (1.0f + expf(-rf.cc));                          \
            rwkv.cc = r * (a / b);                                           \
        }
        WKV1(x) WKV1(y) WKV1(z) WKV1(w)
#undef WKV1

        xs[i] = rwkv;
        if (writer) {
            sa4[i] = sa;
            sb4[i] = sb;
            sp4[i] = sp;
            ns4[i] = x4[i];
        }
    }
    __syncthreads();

    const int wave = t >> 6;
    const int lane = t & 63;
    const int row  = blockIdx.x * 4 + wave;
    const f4* Wrow = (const f4*)(W + (size_t)row * C);

    f4 wreg[16];
#pragma unroll
    for (int it = 0; it < 16; ++it) wreg[it] = Wrow[it * 64 + lane];

    float s0 = 0.f, s1 = 0.f, s2 = 0.f, s3 = 0.f;
#pragma unroll
    for (int it = 0; it < 16; ++it) {
        f4 xx = xs[it * 64 + lane];
        f4 w  = wreg[it];
        s0 += w.x * xx.x;
        s1 += w.y * xx.y;
        s2 += w.z * xx.z;
        s3 += w.w * xx.w;
    }
    float sum = (s0 + s1) + (s2 + s3);
#pragma unroll
    for (int off = 32; off > 0; off >>= 1) sum += __shfl_down(sum, off, 64);
    if (lane == 0) out[row] = sum;
}

// ---------------------------------------------------------------------------
extern "C" void kernel_launch(void* const* d_in, const int* in_sizes, int n_in,
                              void* d_out, int out_size, void* d_ws, size_t ws_size,
                              hipStream_t stream) {
    const float* x          = (const float*)d_in[0];
    const float* state      = (const float*)d_in[1];
    const float* state_a    = (const float*)d_in[2];
    const float* state_b    = (const float*)d_in[3];
    const float* state_p    = (const float*)d_in[4];
    const float* tmk        = (const float*)d_in[5];
    const float* tmv        = (const float*)d_in[6];
    const float* tmr        = (const float*)d_in[7];
    const float* time_first = (const float*)d_in[8];
    const float* time_decay = (const float*)d_in[9];
    const float* kw         = (const float*)d_in[10];
    const float* vw         = (const float*)d_in[11];
    const float* rw         = (const float*)d_in[12];
    const float* ow         = (const float*)d_in[13];

    float* out       = (float*)d_out;        // [0:C)     out
    float* new_state = out + C;              // [C:2C)    new_state = x
    float* new_sa    = out + 2 * C;          // [2C:3C)   new_state_a
    float* new_sb    = out + 3 * C;          // [3C:4C)   new_state_b
    float* new_sp    = out + 4 * C;          // [4C:5C)   new_state_p

    float* ws = (float*)d_ws;
    float* kk = ws;
    float* vv = ws + C;
    float* rr = ws + 2 * C;

    // 1536 blocks = 6/CU; 512 blocks per matrix, 8 rows per block.
    matvec3_kernel<<<3 * C / 8, 256, 0, stream>>>(kw, vw, rw, x, state, tmk, tmv, tmr,
                                                  kk, vv, rr);

    // 1024 blocks = 4/CU; wkv prologue + ow matvec, 1 row per wave.
    wkv_matvec_kernel<<<C / 4, 256, 0, stream>>>(ow, kk, vv, rr,
                                                 state_a, state_b, state_p,
                                                 time_first, time_decay, x,
                                                 out, new_state, new_sa, new_sb, new_sp);
}